// Round 15
// baseline (173.907 us; speedup 1.0000x reference)
//
#include <hip/hip_runtime.h>

// Path signature, depth 4, C=8, L=256, N=256.
// INSTRUMENTATION ROUND: identical R12 computation, repeated REP=8 times
// inside the kernel (each rep fully rewrites LDS state; deterministic).
// Purpose: (1) dur_us = floor + 8*T  ->  T to +-0.6us;
// (2) the sig_kernel dispatch (~8T us) now exceeds the 41us harness fills
// and surfaces in rocprof top-5 with real counters (VGPR/VALUBusy/conflicts).
// Next round: REP=1 + the fix the counters indicate.
// Queued suspicion: ROW=68 (even word stride) => 8-way bank conflict on
// per-lane row-base reads in phase 2; fix candidate ROW=odd.

constexpr int N_SAMP = 256;
constexpr int L_LEN = 256;
constexpr int OUT_PER = 4680;     // 8 + 64 + 512 + 4096
constexpr int NSEG = 8;
constexpr int S4 = 584;           // level-4 offset in signature layout
constexpr int ROW = 68;           // padded row stride for LDS level-4
constexpr int SIG_WORDS = S4 + ROW * 64; // 4936
constexpr int REP = 8;

__global__ __launch_bounds__(512) void sig_kernel(const float* __restrict__ path,
                                                  float* __restrict__ out) {
    __shared__ __align__(16) float dx[(L_LEN - 1) * 8]; // 2040 floats
    __shared__ __align__(16) float X[SIG_WORDS];
    __shared__ __align__(16) float Y[SIG_WORDS];

    const int n = blockIdx.x;
    const int tid = threadIdx.x;
    const float* p = path + (size_t)n * L_LEN * 8;

    const int seg = tid >> 6;   // wave id
    const int r = tid & 63;
    const int i = r >> 3;
    const int j = r & 7;
    const int t0 = seg * 32;
    const int tcnt = (seg == 7) ? 31 : 32;  // wave-uniform
    constexpr float THIRD = 1.f / 3.f;

#pragma unroll 1
    for (int rep = 0; rep < REP; ++rep) {
        // ---- stage increments ----
        if (tid < 510) {
            float4 a = *(const float4*)(p + tid * 4);
            float4 b = *(const float4*)(p + tid * 4 + 8);
            *(float4*)(&dx[tid * 4]) = make_float4(b.x - a.x, b.y - a.y, b.z - a.z, b.w - a.w);
        }
        __syncthreads();

        // ---- phase 1: wave seg computes its segment signature ----
        float acc[8][8];
#pragma unroll
        for (int k = 0; k < 8; ++k)
#pragma unroll
            for (int l = 0; l < 8; ++l) acc[k][l] = 0.f;
        float s3[8] = {0.f, 0.f, 0.f, 0.f, 0.f, 0.f, 0.f, 0.f};
        float s2 = 0.f, s1 = 0.f;

#pragma unroll 2
        for (int t = 0; t < tcnt; ++t) {
            const float* v = &dx[(t0 + t) * 8];
            float4 v0 = *(const float4*)(v);
            float4 v1 = *(const float4*)(v + 4);
            float vv[8] = {v0.x, v0.y, v0.z, v0.w, v1.x, v1.y, v1.z, v1.w};
            float vi = v[i];
            float vj = v[j];

            float c4 = fmaf(vj * THIRD, fmaf(0.25f, vi, s1), s2);
            float c3 = fmaf(vj * 0.5f, fmaf(THIRD, vi, s1), s2);
            float c4h = 0.5f * c4;
#pragma unroll
            for (int k = 0; k < 8; ++k) {
                float f = fmaf(c4h, vv[k], s3[k]);
#pragma unroll
                for (int l = 0; l < 8; ++l) acc[k][l] = fmaf(f, vv[l], acc[k][l]);
                s3[k] = fmaf(c3, vv[k], s3[k]);
            }
            s2 = fmaf(fmaf(0.5f, vi, s1), vj, s2);
            s1 += vi;
        }

        auto write_sig = [&](float* sg) {
            if (j == 0) sg[i] = s1;
            sg[8 + r] = s2;
            *(float4*)(&sg[72 + 8 * r]) = make_float4(s3[0], s3[1], s3[2], s3[3]);
            *(float4*)(&sg[72 + 8 * r + 4]) = make_float4(s3[4], s3[5], s3[6], s3[7]);
            float* rowp = sg + S4 + ROW * r;
#pragma unroll
            for (int k = 0; k < 8; ++k) {
                *(float4*)(rowp + 8 * k) = make_float4(acc[k][0], acc[k][1], acc[k][2], acc[k][3]);
                *(float4*)(rowp + 8 * k + 4) = make_float4(acc[k][4], acc[k][5], acc[k][6], acc[k][7]);
            }
        };

        if (seg == 0) write_sig(X);
        __syncthreads();

        // X4 row (i,j,k=seg) lives in registers across all combines
        float c4r[8];
        {
            const float* q = X + S4 + ROW * r + 8 * seg;
            float4 c0 = *(const float4*)(q);
            float4 c1 = *(const float4*)(q + 4);
            c4r[0] = c0.x; c4r[1] = c0.y; c4r[2] = c0.z; c4r[3] = c0.w;
            c4r[4] = c1.x; c4r[5] = c1.y; c4r[6] = c1.z; c4r[7] = c1.w;
        }

        // ---- phase 2: 7 sequential Chen combines ----
        for (int b = 1; b < NSEG; ++b) {
            if (seg == b) write_sig(Y);
            __syncthreads();

            float4 ya = *(const float4*)(Y);
            float4 yb = *(const float4*)(Y + 4);
            float y1[8] = {ya.x, ya.y, ya.z, ya.w, yb.x, yb.y, yb.z, yb.w};
            const float* y2p = Y + 8 + 8 * seg;
            float4 u0 = *(const float4*)(y2p);
            float4 u1 = *(const float4*)(y2p + 4);
            float y2k[8] = {u0.x, u0.y, u0.z, u0.w, u1.x, u1.y, u1.z, u1.w};
            const float* y3p = Y + 72 + 64 * j + 8 * seg;
            float4 w0 = *(const float4*)(y3p);
            float4 w1 = *(const float4*)(y3p + 4);
            float y3[8] = {w0.x, w0.y, w0.z, w0.w, w1.x, w1.y, w1.z, w1.w};
            const float* y4p = Y + S4 + ROW * r + 8 * seg;
            float4 z0 = *(const float4*)(y4p);
            float4 z1 = *(const float4*)(y4p + 4);
            float y4[8] = {z0.x, z0.y, z0.z, z0.w, z1.x, z1.y, z1.z, z1.w};
            float x3o = X[72 + 8 * r + seg];
            float x2o = X[8 + r];
            float x1o = X[i];

            float n3 = X[72 + tid] + Y[72 + tid];
            n3 = fmaf(X[8 + (tid >> 3)], Y[tid & 7], n3);
            n3 = fmaf(X[tid >> 6], Y[8 + (tid & 63)], n3);
            float n2 = 0.f, n1 = 0.f;
            if (tid < 64) n2 = X[8 + tid] + Y[8 + tid] + X[tid >> 3] * Y[tid & 7];
            if (tid < 8) n1 = X[tid] + Y[tid];

#pragma unroll
            for (int l = 0; l < 8; ++l) {
                float t = c4r[l] + y4[l];
                t = fmaf(x3o, y1[l], t);
                t = fmaf(x2o, y2k[l], t);
                t = fmaf(x1o, y3[l], t);
                c4r[l] = t;
            }

            __syncthreads();
            X[72 + tid] = n3;
            if (tid < 64) X[8 + tid] = n2;
            if (tid < 8) X[tid] = n1;
        }

        // ---- write-out ----
        {
            float* q = Y + S4 + 64 * r + 8 * seg;  // output layout
            *(float4*)(q) = make_float4(c4r[0], c4r[1], c4r[2], c4r[3]);
            *(float4*)(q + 4) = make_float4(c4r[4], c4r[5], c4r[6], c4r[7]);
        }
        __syncthreads();
        float* o = out + (size_t)n * OUT_PER;
        for (int idx = tid; idx < OUT_PER; idx += 512) {
            o[idx] = (idx < S4) ? X[idx] : Y[idx];
        }
        __syncthreads();   // isolate reps
    }
}

extern "C" void kernel_launch(void* const* d_in, const int* in_sizes, int n_in,
                              void* d_out, int out_size, void* d_ws, size_t ws_size,
                              hipStream_t stream) {
    const float* path = (const float*)d_in[0];
    float* out = (float*)d_out;
    sig_kernel<<<N_SAMP, 512, 0, stream>>>(path, out);
}